// Round 1
// 3936.323 us; speedup vs baseline: 1.0571x; 1.0571x over previous
//
#include <hip/hip_runtime.h>
#include <stdint.h>

#define DIM 768
#define NL 13
#define NH 12
#define VOCAB 50257
#define SEQ 512
#define BATCH 4
#define HID 3072
#define HD 64
#define NTOK (BATCH*SEQ)   // 2048
#define BHB (BATCH*NH)     // 48 batched heads

typedef unsigned short u16;
typedef __attribute__((ext_vector_type(8))) __bf16 bf16x8;
typedef __attribute__((ext_vector_type(4))) float f32x4;

__device__ __forceinline__ u16 f2bf(float f) {
    union { float f; uint32_t u; } v; v.f = f;
    uint32_t u = v.u;
    return (u16)((u + 0x7FFFu + ((u >> 16) & 1u)) >> 16);   // RNE
}

__device__ __forceinline__ void gl2lds16(const void* g, void* l) {
    // async global->LDS, 16B/lane; LDS dest = wave-uniform base + lane*16
    __builtin_amdgcn_global_load_lds((const __attribute__((address_space(1))) void*)g,
                                     (__attribute__((address_space(3))) void*)l,
                                     16, 0, 0);
}

__device__ __forceinline__ float gelu_tanh(float x) {
    float x3 = x * x * x;
    float t = tanhf(0.7978845608028654f * (x + 0.044715f * x3));
    return 0.5f * x * (1.0f + t);
}

// ---------------------------------------------------------------------------
// GEMM: C = A @ B^T.  A:[M,K] bf16 row-major, B:[N,K] bf16 row-major.
// 128 x (WN*32) tile, BK=32, 256 threads = 4 waves in 2x2, wave does 64 x (WN*16).
// v2: double-buffered LDS (2-phase pipeline, 1 barrier/K-step),
//     XOR k-chunk swizzle (kills the 8-way ds_read_b128 bank conflict;
//     source-side pre-swizzle since global_load_lds writes linearly),
//     bijective XCD-aware block remap for L2 locality.
// EPI: 0 plain f32 (col-bound checked), 1 qkv scatter, 2 attn-out scatter,
//      3 f32 + bias + residual, 4 gelu -> bf16
// ---------------------------------------------------------------------------
template<int WN, int EPI>
__global__ __launch_bounds__(256)
void gemm_bt(const u16* __restrict__ A, const u16* __restrict__ B,
             const float* __restrict__ bias, const float* __restrict__ resid,
             void* __restrict__ out0, void* __restrict__ out1, void* __restrict__ out2,
             int M, int N, int K, long sA, long sB, long sC)
{
    constexpr int TN = WN * 32;
    __shared__ u16 As[2 * 128 * 32];
    __shared__ u16 Bs[2 * TN * 32];

    const int tid  = threadIdx.x;
    const int wave = tid >> 6;
    const int lane = tid & 63;
    const int quad = lane >> 4;
    const int l16  = lane & 15;
    const int wm   = wave >> 1;
    const int wn   = wave & 1;

    // XCD-aware bijective remap (m204): consecutive tile-ids (which share a
    // B panel, x-fastest) land on the same XCD's L2 instead of round-robin.
    int bx = blockIdx.x, by = blockIdx.y;
    {
        const int gx = gridDim.x;
        const int nwg = gx * gridDim.y;
        const int orig = by * gx + bx;
        const int xcd = orig & 7;
        const int q = nwg >> 3, r = nwg & 7;
        const int wg = (xcd < r ? xcd * (q + 1) : r * (q + 1) + (xcd - r) * q) + (orig >> 3);
        bx = wg % gx; by = wg / gx;
    }

    const int m0 = bx * 128;
    const int n0 = by * TN;
    const int z  = blockIdx.z;

    const u16* Ab = A + (long)z * sA;
    const u16* Bb = B + (long)z * sB;

    // staging: lane -> (row = tid>>2, k-chunk = tid&3), 16B each.
    // SWIZZLE: LDS[row][c] must hold global chunk c ^ s(row), s(row)=(row>>1)&3.
    // global_load_lds writes linearly, so permute the SOURCE k-chunk instead.
    const int srow = tid >> 2;          // 0..63
    const int scol = ((tid & 3) ^ ((srow >> 1) & 3)) * 8;   // pre-swizzled k-chunk

    u16* const asw0 = As + wave * 512;          // rows  0..63 (this wave's 16 rows)
    u16* const asw1 = As + 2048 + wave * 512;   // rows 64..127
    u16* const bsw0 = Bs + wave * 512;
    u16* const bsw1 = Bs + 2048 + wave * 512;   // WN==4 only

    const long aoff0 = (long)(m0 + srow) * K + scol;
    const long aoff1 = (long)(m0 + 64 + srow) * K + scol;
    int br0 = n0 + srow;      if (br0 > N - 1) br0 = N - 1;
    int br1 = n0 + 64 + srow; if (br1 > N - 1) br1 = N - 1;
    const long boff0 = (long)br0 * K + scol;
    const long boff1 = (long)br1 * K + scol;

    auto stage = [&](int b, int k0) {
        const int ao = b * 4096;
        const int bo = b * (TN * 32);
        gl2lds16(Ab + aoff0 + k0, asw0 + ao);
        gl2lds16(Ab + aoff1 + k0, asw1 + ao);
        gl2lds16(Bb + boff0 + k0, bsw0 + bo);
        if constexpr (WN == 4) gl2lds16(Bb + boff1 + k0, bsw1 + bo);
    };

    f32x4 acc[4][WN];
    #pragma unroll
    for (int i = 0; i < 4; i++)
        #pragma unroll
        for (int j = 0; j < WN; j++)
            acc[i][j] = (f32x4){0.f, 0.f, 0.f, 0.f};

    // read-side swizzle: for rows wm*64+i*16+l16 (and B rows), (row>>1)&3 == (l16>>1)&3
    const int sq8 = (quad ^ ((l16 >> 1) & 3)) * 8;
    const int arow = (wm * 64 + l16) * 32 + sq8;
    const int brow = (wn * (WN * 16) + l16) * 32 + sq8;

    // prologue: fill buffer 0
    stage(0, 0);
    __syncthreads();

    int cur = 0;
    for (int k0 = 0; k0 < K; k0 += 32) {
        if (k0 + 32 < K) stage(cur ^ 1, k0 + 32);   // prefetch overlaps compute below

        const u16* Ar = As + cur * 4096;
        const u16* Br = Bs + cur * (TN * 32);
        bf16x8 af[4], bfr[WN];
        #pragma unroll
        for (int i = 0; i < 4; i++)
            af[i] = *(const bf16x8*)&Ar[arow + i * 512];
        #pragma unroll
        for (int j = 0; j < WN; j++)
            bfr[j] = *(const bf16x8*)&Br[brow + j * 512];
        #pragma unroll
        for (int i = 0; i < 4; i++)
            #pragma unroll
            for (int j = 0; j < WN; j++)
                acc[i][j] = __builtin_amdgcn_mfma_f32_16x16x32_bf16(af[i], bfr[j], acc[i][j], 0, 0, 0);

        __syncthreads();   // drains prefetch (vmcnt) + guards buffer reuse; 1 barrier/step
        cur ^= 1;
    }

    const int rbase = m0 + wm * 64;
    const int cbase = n0 + wn * (WN * 16);
    #pragma unroll
    for (int i = 0; i < 4; i++) {
        #pragma unroll
        for (int j = 0; j < WN; j++) {
            #pragma unroll
            for (int rg = 0; rg < 4; rg++) {
                const int r = rbase + i * 16 + quad * 4 + rg;
                const int c = cbase + j * 16 + l16;
                float v = acc[i][j][rg];
                if constexpr (EPI == 0) {
                    if (c < N) ((float*)out0)[(long)z * sC + (long)r * N + c] = v;
                } else if constexpr (EPI == 1) {
                    v += bias[c];
                    const int part = c / DIM;
                    const int cc = c - part * DIM;
                    const int hh = cc >> 6, d = cc & 63;
                    const int b = r >> 9, t = r & 511;
                    const int bh = b * NH + hh;
                    if (part == 0)      ((u16*)out0)[((long)bh * SEQ + t) * HD + d] = f2bf(v);
                    else if (part == 1) ((u16*)out1)[((long)bh * SEQ + t) * HD + d] = f2bf(v);
                    else                ((u16*)out2)[((long)bh * HD + d) * SEQ + t] = f2bf(v);
                } else if constexpr (EPI == 2) {
                    const int b = z / NH, hh = z - b * NH;
                    ((u16*)out0)[((long)b * SEQ + r) * DIM + hh * HD + c] = f2bf(v);
                } else if constexpr (EPI == 3) {
                    if (bias) v += bias[c];
                    v += resid[(long)r * N + c];
                    ((float*)out0)[(long)r * N + c] = v;
                } else {
                    ((u16*)out0)[(long)r * N + c] = f2bf(gelu_tanh(v));
                }
            }
        }
    }
}

// x = tok_emb[idx] + pos_emb ; fp32 out
__global__ __launch_bounds__(256)
void embed_kernel(const int* __restrict__ tokidx, const float* __restrict__ tok,
                  const float* __restrict__ pos, float* __restrict__ x)
{
    const int i = blockIdx.x * 256 + threadIdx.x;   // float4 index over NTOK*192
    const int row = i / 192;
    const int c4 = i - row * 192;
    const int t = row & (SEQ - 1);
    const int tk = tokidx[row];
    const float4 a = *(const float4*)&tok[(long)tk * DIM + c4 * 4];
    const float4 p = *(const float4*)&pos[(long)t * DIM + c4 * 4];
    *(float4*)&x[(long)row * DIM + c4 * 4] = make_float4(a.x + p.x, a.y + p.y, a.z + p.z, a.w + p.w);
}

// LayerNorm over DIM=768, one wave per row, bf16 out
__global__ __launch_bounds__(256)
void ln_kernel(const float* __restrict__ x, const float* __restrict__ g,
               const float* __restrict__ b, u16* __restrict__ out)
{
    const int row = blockIdx.x * 4 + (threadIdx.x >> 6);
    const int lane = threadIdx.x & 63;
    const float* xr = x + (long)row * DIM;
    float v[12];
    float s = 0.f, s2 = 0.f;
    #pragma unroll
    for (int i = 0; i < 3; i++) {
        const float4 f = *(const float4*)&xr[i * 256 + lane * 4];
        v[i*4+0] = f.x; v[i*4+1] = f.y; v[i*4+2] = f.z; v[i*4+3] = f.w;
        s  += f.x + f.y + f.z + f.w;
        s2 += f.x*f.x + f.y*f.y + f.z*f.z + f.w*f.w;
    }
    for (int o = 32; o; o >>= 1) { s += __shfl_xor(s, o); s2 += __shfl_xor(s2, o); }
    const float m  = s * (1.f / DIM);
    const float var = s2 * (1.f / DIM) - m * m;
    const float rs = rsqrtf(var + 1e-5f);
    u16* orow = out + (long)row * DIM;
    #pragma unroll
    for (int i = 0; i < 3; i++) {
        const int c = i * 256 + lane * 4;
        ushort4 o4 = make_ushort4(
            f2bf((v[i*4+0] - m) * rs * g[c+0] + b[c+0]),
            f2bf((v[i*4+1] - m) * rs * g[c+1] + b[c+1]),
            f2bf((v[i*4+2] - m) * rs * g[c+2] + b[c+2]),
            f2bf((v[i*4+3] - m) * rs * g[c+3] + b[c+3]));
        *(ushort4*)&orow[c] = o4;
    }
}

// causal softmax over SEQ=512 scores (scale 1/8 folded in), bf16 out (zeros where masked)
__global__ __launch_bounds__(256)
void softmax_kernel(const float* __restrict__ S, u16* __restrict__ P)
{
    const int row = blockIdx.x * 4 + (threadIdx.x >> 6);  // over BHB*SEQ
    const int lane = threadIdx.x & 63;
    const int t = row & (SEQ - 1);
    const float* sr = S + (long)row * SEQ;
    float v[8];
    #pragma unroll
    for (int i = 0; i < 2; i++) {
        const int c = i * 256 + lane * 4;
        const float4 f = *(const float4*)&sr[c];
        v[i*4+0] = (c + 0 <= t) ? f.x * 0.125f : -1e30f;
        v[i*4+1] = (c + 1 <= t) ? f.y * 0.125f : -1e30f;
        v[i*4+2] = (c + 2 <= t) ? f.z * 0.125f : -1e30f;
        v[i*4+3] = (c + 3 <= t) ? f.w * 0.125f : -1e30f;
    }
    float mx = -1e30f;
    #pragma unroll
    for (int i = 0; i < 8; i++) mx = fmaxf(mx, v[i]);
    for (int o = 32; o; o >>= 1) mx = fmaxf(mx, __shfl_xor(mx, o));
    float sum = 0.f;
    #pragma unroll
    for (int i = 0; i < 8; i++) { const float e = __expf(v[i] - mx); v[i] = e; sum += e; }
    for (int o = 32; o; o >>= 1) sum += __shfl_xor(sum, o);
    const float inv = 1.f / sum;
    u16* pr = P + (long)row * SEQ;
    #pragma unroll
    for (int i = 0; i < 2; i++) {
        const int c = i * 256 + lane * 4;
        *(ushort4*)&pr[c] = make_ushort4(f2bf(v[i*4+0] * inv), f2bf(v[i*4+1] * inv),
                                         f2bf(v[i*4+2] * inv), f2bf(v[i*4+3] * inv));
    }
}

// fp32 -> bf16 bulk convert (grid covers total/4 exactly)
__global__ __launch_bounds__(256)
void tobf16_kernel(const float* __restrict__ in, u16* __restrict__ out)
{
    const long i = ((long)blockIdx.x * 256 + threadIdx.x) * 4;
    const float4 f = *(const float4*)&in[i];
    *(ushort4*)&out[i] = make_ushort4(f2bf(f.x), f2bf(f.y), f2bf(f.z), f2bf(f.w));
}

// ghost dequant: w[o,k] = bf16(lut[idx[o,k]] * scale[o])
__global__ __launch_bounds__(256)
void dequant_kernel(const int* __restrict__ gidx, const float* __restrict__ scale,
                    const float* __restrict__ lut, u16* __restrict__ w,
                    long total, int Kd)
{
    __shared__ float slut[256];
    slut[threadIdx.x] = lut[threadIdx.x];
    __syncthreads();
    const long i4 = ((long)blockIdx.x * 256 + threadIdx.x) * 4;
    if (i4 >= total) return;
    const int4 g = *(const int4*)&gidx[i4];
    const float sc = scale[(int)(i4 / Kd)];
    *(ushort4*)&w[i4] = make_ushort4(f2bf(slut[g.x] * sc), f2bf(slut[g.y] * sc),
                                     f2bf(slut[g.z] * sc), f2bf(slut[g.w] * sc));
}

extern "C" void kernel_launch(void* const* d_in, const int* in_sizes, int n_in,
                              void* d_out, int out_size, void* d_ws, size_t ws_size,
                              hipStream_t stream)
{
    const float* lut        = (const float*)d_in[0];
    const float* tok_emb    = (const float*)d_in[1];
    const float* pos_emb    = (const float*)d_in[2];
    const float* ln1_g      = (const float*)d_in[3];
    const float* ln1_b      = (const float*)d_in[4];
    const float* in_w       = (const float*)d_in[5];
    const float* in_b       = (const float*)d_in[6];
    const float* out_w      = (const float*)d_in[7];
    const float* out_b      = (const float*)d_in[8];
    const float* ln2_g      = (const float*)d_in[9];
    const float* ln2_b      = (const float*)d_in[10];
    const float* mlp1_scale = (const float*)d_in[11];
    const float* mlp2_scale = (const float*)d_in[12];
    const float* lnf_g      = (const float*)d_in[13];
    const float* lnf_b      = (const float*)d_in[14];
    const float* head_scale = (const float*)d_in[15];
    const int*   mlp1_idx   = (const int*)d_in[16];
    const int*   mlp2_idx   = (const int*)d_in[17];
    const int*   head_idx   = (const int*)d_in[18];
    const int*   tokids     = (const int*)d_in[19];

    char* p = (char*)d_ws;
    auto alloc = [&](size_t bytes) { char* r = p; p += (bytes + 255) & ~(size_t)255; return r; };
    float* x    = (float*)alloc((size_t)NTOK * DIM * 4);
    u16*  h     = (u16*) alloc((size_t)NTOK * DIM * 2);
    u16*  h2    = (u16*) alloc((size_t)NTOK * HID * 2);
    u16*  qb    = (u16*) alloc((size_t)BHB * SEQ * HD * 2);
    u16*  kb    = (u16*) alloc((size_t)BHB * SEQ * HD * 2);
    u16*  vtb   = (u16*) alloc((size_t)BHB * SEQ * HD * 2);
    float* S    = (float*)alloc((size_t)BHB * SEQ * SEQ * 4);
    u16*  P     = (u16*) alloc((size_t)BHB * SEQ * SEQ * 2);
    u16*  ob    = (u16*) alloc((size_t)NTOK * DIM * 2);
    u16*  inw16 = (u16*) alloc((size_t)NL * 3 * DIM * DIM * 2);
    u16*  outw16= (u16*) alloc((size_t)NL * DIM * DIM * 2);
    u16*  w1    = (u16*) alloc((size_t)HID * DIM * 2);
    u16*  w2    = (u16*) alloc((size_t)DIM * HID * 2);
    u16*  hw    = (u16*) alloc((size_t)VOCAB * DIM * 2);

    embed_kernel<<<NTOK * 192 / 256, 256, 0, stream>>>(tokids, tok_emb, pos_emb, x);
    tobf16_kernel<<<NL * 3 * DIM * DIM / 1024, 256, 0, stream>>>(in_w, inw16);
    tobf16_kernel<<<NL * DIM * DIM / 1024, 256, 0, stream>>>(out_w, outw16);
    {
        const long total = (long)VOCAB * DIM;
        const int blocks = (int)((total / 4 + 255) / 256);
        dequant_kernel<<<blocks, 256, 0, stream>>>(head_idx, head_scale, lut, hw, total, DIM);
    }

    for (int l = 0; l < NL; l++) {
        ln_kernel<<<NTOK / 4, 256, 0, stream>>>(x, ln1_g + l * DIM, ln1_b + l * DIM, h);
        gemm_bt<4, 1><<<dim3(NTOK / 128, 3 * DIM / 128, 1), 256, 0, stream>>>(
            h, inw16 + (long)l * 3 * DIM * DIM, in_b + l * 3 * DIM, nullptr,
            qb, kb, vtb, NTOK, 3 * DIM, DIM, 0, 0, 0);
        gemm_bt<4, 0><<<dim3(SEQ / 128, SEQ / 128, BHB), 256, 0, stream>>>(
            qb, kb, nullptr, nullptr, S, nullptr, nullptr,
            SEQ, SEQ, HD, (long)SEQ * HD, (long)SEQ * HD, (long)SEQ * SEQ);
        softmax_kernel<<<BHB * SEQ / 4, 256, 0, stream>>>(S, P);
        gemm_bt<2, 2><<<dim3(SEQ / 128, 1, BHB), 256, 0, stream>>>(
            P, vtb, nullptr, nullptr, ob, nullptr, nullptr,
            SEQ, HD, SEQ, (long)SEQ * SEQ, (long)HD * SEQ, 0);
        gemm_bt<4, 3><<<dim3(NTOK / 128, DIM / 128, 1), 256, 0, stream>>>(
            ob, outw16 + (long)l * DIM * DIM, out_b + l * DIM, x,
            x, nullptr, nullptr, NTOK, DIM, DIM, 0, 0, 0);
        ln_kernel<<<NTOK / 4, 256, 0, stream>>>(x, ln2_g + l * DIM, ln2_b + l * DIM, h);
        dequant_kernel<<<HID * DIM / 1024, 256, 0, stream>>>(
            mlp1_idx + (long)l * HID * DIM, mlp1_scale + l * HID, lut, w1, (long)HID * DIM, DIM);
        gemm_bt<4, 4><<<dim3(NTOK / 128, HID / 128, 1), 256, 0, stream>>>(
            h, w1, nullptr, nullptr, h2, nullptr, nullptr, NTOK, HID, DIM, 0, 0, 0);
        dequant_kernel<<<DIM * HID / 1024, 256, 0, stream>>>(
            mlp2_idx + (long)l * DIM * HID, mlp2_scale + l * DIM, lut, w2, (long)DIM * HID, HID);
        gemm_bt<4, 3><<<dim3(NTOK / 128, DIM / 128, 1), 256, 0, stream>>>(
            h2, w2, nullptr, x, x, nullptr, nullptr, NTOK, DIM, HID, 0, 0, 0);
    }

    ln_kernel<<<NTOK / 4, 256, 0, stream>>>(x, lnf_g, lnf_b, h);
    gemm_bt<4, 0><<<dim3(NTOK / 128, (VOCAB + 127) / 128, 1), 256, 0, stream>>>(
        h, hw, nullptr, nullptr, d_out, nullptr, nullptr, NTOK, VOCAB, DIM, 0, 0, 0);
}

// Round 2
// 3323.811 us; speedup vs baseline: 1.2519x; 1.1843x over previous
//
#include <hip/hip_runtime.h>
#include <stdint.h>

#define DIM 768
#define NL 13
#define NH 12
#define VOCAB 50257
#define SEQ 512
#define BATCH 4
#define HID 3072
#define HD 64
#define NTOK (BATCH*SEQ)   // 2048
#define BHB (BATCH*NH)     // 48 batched heads

typedef unsigned short u16;
typedef __attribute__((ext_vector_type(8))) __bf16 bf16x8;
typedef __attribute__((ext_vector_type(4))) float f32x4;

__device__ __forceinline__ u16 f2bf(float f) {
    union { float f; uint32_t u; } v; v.f = f;
    uint32_t u = v.u;
    return (u16)((u + 0x7FFFu + ((u >> 16) & 1u)) >> 16);   // RNE
}

__device__ __forceinline__ void gl2lds16(const void* g, void* l) {
    // async global->LDS, 16B/lane; LDS dest = wave-uniform base + lane*16
    __builtin_amdgcn_global_load_lds((const __attribute__((address_space(1))) void*)g,
                                     (__attribute__((address_space(3))) void*)l,
                                     16, 0, 0);
}

__device__ __forceinline__ float gelu_tanh(float x) {
    float x3 = x * x * x;
    float t = tanhf(0.7978845608028654f * (x + 0.044715f * x3));
    return 0.5f * x * (1.0f + t);
}

// ---------------------------------------------------------------------------
// GEMM: C = A @ B^T.  A:[M,K] bf16 row-major, B:[N,K] bf16 row-major.
// 128 x (WN*32) tile, BK=32, 256 threads = 4 waves in 2x2, wave does 64 x (WN*16).
// double-buffered LDS, XOR k-chunk swizzle (source-side pre-swizzle for
// global_load_lds), bijective XCD-aware block remap.
// EPI: 0 plain f32 (col-bound checked), 1 qkv scatter, 3 f32 + bias + residual,
//      4 gelu -> bf16
// ---------------------------------------------------------------------------
template<int WN, int EPI>
__global__ __launch_bounds__(256)
void gemm_bt(const u16* __restrict__ A, const u16* __restrict__ B,
             const float* __restrict__ bias, const float* __restrict__ resid,
             void* __restrict__ out0, void* __restrict__ out1, void* __restrict__ out2,
             int M, int N, int K, long sA, long sB, long sC)
{
    constexpr int TN = WN * 32;
    __shared__ __align__(16) u16 As[2 * 128 * 32];
    __shared__ __align__(16) u16 Bs[2 * TN * 32];

    const int tid  = threadIdx.x;
    const int wave = tid >> 6;
    const int lane = tid & 63;
    const int quad = lane >> 4;
    const int l16  = lane & 15;
    const int wm   = wave >> 1;
    const int wn   = wave & 1;

    int bx = blockIdx.x, by = blockIdx.y;
    {
        const int gx = gridDim.x;
        const int nwg = gx * gridDim.y;
        const int orig = by * gx + bx;
        const int xcd = orig & 7;
        const int q = nwg >> 3, r = nwg & 7;
        const int wg = (xcd < r ? xcd * (q + 1) : r * (q + 1) + (xcd - r) * q) + (orig >> 3);
        bx = wg % gx; by = wg / gx;
    }

    const int m0 = bx * 128;
    const int n0 = by * TN;
    const int z  = blockIdx.z;

    const u16* Ab = A + (long)z * sA;
    const u16* Bb = B + (long)z * sB;

    const int srow = tid >> 2;          // 0..63
    const int scol = ((tid & 3) ^ ((srow >> 1) & 3)) * 8;   // pre-swizzled k-chunk

    u16* const asw0 = As + wave * 512;
    u16* const asw1 = As + 2048 + wave * 512;
    u16* const bsw0 = Bs + wave * 512;
    u16* const bsw1 = Bs + 2048 + wave * 512;   // WN==4 only

    const long aoff0 = (long)(m0 + srow) * K + scol;
    const long aoff1 = (long)(m0 + 64 + srow) * K + scol;
    int br0 = n0 + srow;      if (br0 > N - 1) br0 = N - 1;
    int br1 = n0 + 64 + srow; if (br1 > N - 1) br1 = N - 1;
    const long boff0 = (long)br0 * K + scol;
    const long boff1 = (long)br1 * K + scol;

    auto stage = [&](int b, int k0) {
        const int ao = b * 4096;
        const int bo = b * (TN * 32);
        gl2lds16(Ab + aoff0 + k0, asw0 + ao);
        gl2lds16(Ab + aoff1 + k0, asw1 + ao);
        gl2lds16(Bb + boff0 + k0, bsw0 + bo);
        if constexpr (WN == 4) gl2lds16(Bb + boff1 + k0, bsw1 + bo);
    };

    f32x4 acc[4][WN];
    #pragma unroll
    for (int i = 0; i < 4; i++)
        #pragma unroll
        for (int j = 0; j < WN; j++)
            acc[i][j] = (f32x4){0.f, 0.f, 0.f, 0.f};

    const int sq8 = (quad ^ ((l16 >> 1) & 3)) * 8;
    const int arow = (wm * 64 + l16) * 32 + sq8;
    const int brow = (wn * (WN * 16) + l16) * 32 + sq8;

    stage(0, 0);
    __syncthreads();

    int cur = 0;
    for (int k0 = 0; k0 < K; k0 += 32) {
        if (k0 + 32 < K) stage(cur ^ 1, k0 + 32);

        const u16* Ar = As + cur * 4096;
        const u16* Br = Bs + cur * (TN * 32);
        bf16x8 af[4], bfr[WN];
        #pragma unroll
        for (int i = 0; i < 4; i++)
            af[i] = *(const bf16x8*)&Ar[arow + i * 512];
        #pragma unroll
        for (int j = 0; j < WN; j++)
            bfr[j] = *(const bf16x8*)&Br[brow + j * 512];
        #pragma unroll
        for (int i = 0; i < 4; i++)
            #pragma unroll
            for (int j = 0; j < WN; j++)
                acc[i][j] = __builtin_amdgcn_mfma_f32_16x16x32_bf16(af[i], bfr[j], acc[i][j], 0, 0, 0);

        __syncthreads();
        cur ^= 1;
    }

    const int rbase = m0 + wm * 64;
    const int cbase = n0 + wn * (WN * 16);
    #pragma unroll
    for (int i = 0; i < 4; i++) {
        #pragma unroll
        for (int j = 0; j < WN; j++) {
            #pragma unroll
            for (int rg = 0; rg < 4; rg++) {
                const int r = rbase + i * 16 + quad * 4 + rg;
                const int c = cbase + j * 16 + l16;
                float v = acc[i][j][rg];
                if constexpr (EPI == 0) {
                    if (c < N) ((float*)out0)[(long)z * sC + (long)r * N + c] = v;
                } else if constexpr (EPI == 1) {
                    v += bias[c];
                    const int part = c / DIM;
                    const int cc = c - part * DIM;
                    const int hh = cc >> 6, d = cc & 63;
                    const int b = r >> 9, t = r & 511;
                    const int bh = b * NH + hh;
                    if (part == 0)      ((u16*)out0)[((long)bh * SEQ + t) * HD + d] = f2bf(v);
                    else if (part == 1) ((u16*)out1)[((long)bh * SEQ + t) * HD + d] = f2bf(v);
                    else                ((u16*)out2)[((long)bh * HD + d) * SEQ + t] = f2bf(v);
                } else if constexpr (EPI == 3) {
                    if (bias) v += bias[c];
                    v += resid[(long)r * N + c];
                    ((float*)out0)[(long)r * N + c] = v;
                } else {
                    ((u16*)out0)[(long)r * N + c] = f2bf(gelu_tanh(v));
                }
            }
        }
    }
}

// ---------------------------------------------------------------------------
// Fused flash attention.  Grid (BHB, 4): x = head (so a head's 4 q-blocks share
// an XCD under round-robin, 48%8==0), y = q-block of 128 rows.  4 waves, each
// owns 32 q-rows and loops its causal KV range independently (no barriers in
// the loop).  K[512][64] and V^T[64][512] preloaded to LDS, XOR-chunk-swizzled
// via pre-swizzled global_load_lds source.  Online softmax in-register; P
// re-fragmented through a per-wave swizzled LDS buffer.
// ---------------------------------------------------------------------------
__global__ __launch_bounds__(256)
void attn_kernel(const u16* __restrict__ qb, const u16* __restrict__ kb,
                 const u16* __restrict__ vtb, u16* __restrict__ ob)
{
    __shared__ __align__(16) u16 Ks[512 * 64];     // 64KB  [kv][d]
    __shared__ __align__(16) u16 Vs[64 * 512];     // 64KB  [d][kv] (V^T)
    __shared__ __align__(16) u16 Ps[4][32 * 64];   // 16KB  per-wave P tile

    const int tid  = threadIdx.x;
    const int wave = tid >> 6;
    const int lane = tid & 63;
    const int quad = lane >> 4;
    const int l16  = lane & 15;

    const int bh   = blockIdx.x;
    const int qblk = blockIdx.y;
    const int qr0  = qblk * 128 + wave * 32;

    // ---- stage K: 16 calls/wave, 8 rows (1KB) each; LDS(r,c)=global chunk c^(r&7)
    #pragma unroll 4
    for (int cI = 0; cI < 16; ++cI) {
        const int rbase = cI * 32 + wave * 8;
        const int r  = rbase + (lane >> 3);
        const int ch = lane & 7;
        gl2lds16(kb + ((long)bh * SEQ + r) * HD + ((ch ^ (r & 7)) * 8), Ks + rbase * 64);
    }
    // ---- stage V^T: 16 calls/wave, 1 d-row (1KB) each; LDS(d,c)=global chunk c^(d&7)
    #pragma unroll 4
    for (int cI = 0; cI < 16; ++cI) {
        const int d = cI * 4 + wave;
        gl2lds16(vtb + ((long)bh * HD + d) * SEQ + ((lane ^ (d & 7)) * 8), Vs + d * 512);
    }

    // ---- Q fragments (A-operand) straight from global
    bf16x8 af[2][2];
    const long qoff = ((long)bh * SEQ + qr0) * HD;
    #pragma unroll
    for (int i = 0; i < 2; i++)
        #pragma unroll
        for (int kc = 0; kc < 2; kc++)
            af[i][kc] = *(const bf16x8*)&qb[qoff + (long)(i * 16 + l16) * HD + kc * 32 + quad * 8];

    __syncthreads();   // drains vmcnt for the LDS staging

    f32x4 o[2][4];
    float mrun[2][4], lrun[2][4];
    #pragma unroll
    for (int i = 0; i < 2; i++)
        #pragma unroll
        for (int rg = 0; rg < 4; rg++) { mrun[i][rg] = -1e30f; lrun[i][rg] = 0.f; }
    #pragma unroll
    for (int i = 0; i < 2; i++)
        #pragma unroll
        for (int nd = 0; nd < 4; nd++)
            o[i][nd] = (f32x4){0.f, 0.f, 0.f, 0.f};

    u16* const Pw = &Ps[wave][0];
    const int rsw = l16 & 7;          // row-parity swizzle used on all reads
    const int kvend = qr0 + 32;       // causal bound for this wave

    for (int kv0 = 0; kv0 < kvend; kv0 += 64) {
        // ---- S = Q @ K^T (32 x 64 per wave)
        f32x4 s[2][4];
        #pragma unroll
        for (int i = 0; i < 2; i++)
            #pragma unroll
            for (int n = 0; n < 4; n++)
                s[i][n] = (f32x4){0.f, 0.f, 0.f, 0.f};
        bf16x8 bf[4][2];
        #pragma unroll
        for (int n = 0; n < 4; n++)
            #pragma unroll
            for (int kc = 0; kc < 2; kc++)
                bf[n][kc] = *(const bf16x8*)&Ks[(kv0 + n * 16 + l16) * 64 + (((kc * 4 + quad) ^ rsw) * 8)];
        #pragma unroll
        for (int i = 0; i < 2; i++)
            #pragma unroll
            for (int n = 0; n < 4; n++)
                #pragma unroll
                for (int kc = 0; kc < 2; kc++)
                    s[i][n] = __builtin_amdgcn_mfma_f32_16x16x32_bf16(af[i][kc], bf[n][kc], s[i][n], 0, 0, 0);

        // ---- mask + online softmax + P write (per (i,rg) = one q-row / lane group)
        #pragma unroll
        for (int i = 0; i < 2; i++) {
            #pragma unroll
            for (int rg = 0; rg < 4; rg++) {
                const int q = qr0 + i * 16 + quad * 4 + rg;
                float v[4];
                #pragma unroll
                for (int n = 0; n < 4; n++) {
                    const int c = kv0 + n * 16 + l16;
                    v[n] = (c <= q) ? s[i][n][rg] * 0.125f : -1e30f;
                }
                float pm = fmaxf(fmaxf(v[0], v[1]), fmaxf(v[2], v[3]));
                #pragma unroll
                for (int off = 1; off < 16; off <<= 1) pm = fmaxf(pm, __shfl_xor(pm, off));
                const float mo = mrun[i][rg];
                const float mn = fmaxf(mo, pm);
                const float corr = __expf(mo - mn);
                float ps = 0.f;
                #pragma unroll
                for (int n = 0; n < 4; n++) { const float e = __expf(v[n] - mn); v[n] = e; ps += e; }
                #pragma unroll
                for (int off = 1; off < 16; off <<= 1) ps += __shfl_xor(ps, off);
                lrun[i][rg] = lrun[i][rg] * corr + ps;
                mrun[i][rg] = mn;
                #pragma unroll
                for (int nd = 0; nd < 4; nd++) o[i][nd][rg] *= corr;
                const int qlz = i * 16 + quad * 4 + rg;
                const int sw = qlz & 7;
                #pragma unroll
                for (int n = 0; n < 4; n++)
                    Pw[qlz * 64 + (((n * 2 + (l16 >> 3)) ^ sw) * 8) + (l16 & 7)] = f2bf(v[n]);
            }
        }
        asm volatile("s_waitcnt lgkmcnt(0)" ::: "memory");   // P writes visible wave-wide

        // ---- O += P @ V  (A = P from LDS, B = V^T rows from LDS)
        bf16x8 pa[2][2], vb[4][2];
        #pragma unroll
        for (int i = 0; i < 2; i++)
            #pragma unroll
            for (int kc = 0; kc < 2; kc++)
                pa[i][kc] = *(const bf16x8*)&Pw[(i * 16 + l16) * 64 + (((kc * 4 + quad) ^ rsw) * 8)];
        #pragma unroll
        for (int nd = 0; nd < 4; nd++)
            #pragma unroll
            for (int kc = 0; kc < 2; kc++)
                vb[nd][kc] = *(const bf16x8*)&Vs[(nd * 16 + l16) * 512 + ((((kv0 >> 3) + kc * 4 + quad) ^ rsw) * 8)];
        #pragma unroll
        for (int i = 0; i < 2; i++)
            #pragma unroll
            for (int nd = 0; nd < 4; nd++)
                #pragma unroll
                for (int kc = 0; kc < 2; kc++)
                    o[i][nd] = __builtin_amdgcn_mfma_f32_16x16x32_bf16(pa[i][kc], vb[nd][kc], o[i][nd], 0, 0, 0);
    }

    // ---- normalize + store (ob is [B][SEQ][DIM] bf16, head slice)
    const int b  = bh / NH, hh = bh - b * NH;
    #pragma unroll
    for (int i = 0; i < 2; i++) {
        #pragma unroll
        for (int rg = 0; rg < 4; rg++) {
            const float inv = 1.f / lrun[i][rg];
            const int t = qr0 + i * 16 + quad * 4 + rg;
            u16* orow = ob + ((long)(b * SEQ + t)) * DIM + hh * HD;
            #pragma unroll
            for (int nd = 0; nd < 4; nd++)
                orow[nd * 16 + l16] = f2bf(o[i][nd][rg] * inv);
        }
    }
}

// x = tok_emb[idx] + pos_emb ; fp32 out
__global__ __launch_bounds__(256)
void embed_kernel(const int* __restrict__ tokidx, const float* __restrict__ tok,
                  const float* __restrict__ pos, float* __restrict__ x)
{
    const int i = blockIdx.x * 256 + threadIdx.x;   // float4 index over NTOK*192
    const int row = i / 192;
    const int c4 = i - row * 192;
    const int t = row & (SEQ - 1);
    const int tk = tokidx[row];
    const float4 a = *(const float4*)&tok[(long)tk * DIM + c4 * 4];
    const float4 p = *(const float4*)&pos[(long)t * DIM + c4 * 4];
    *(float4*)&x[(long)row * DIM + c4 * 4] = make_float4(a.x + p.x, a.y + p.y, a.z + p.z, a.w + p.w);
}

// LayerNorm over DIM=768, one wave per row, bf16 out
__global__ __launch_bounds__(256)
void ln_kernel(const float* __restrict__ x, const float* __restrict__ g,
               const float* __restrict__ b, u16* __restrict__ out)
{
    const int row = blockIdx.x * 4 + (threadIdx.x >> 6);
    const int lane = threadIdx.x & 63;
    const float* xr = x + (long)row * DIM;
    float v[12];
    float s = 0.f, s2 = 0.f;
    #pragma unroll
    for (int i = 0; i < 3; i++) {
        const float4 f = *(const float4*)&xr[i * 256 + lane * 4];
        v[i*4+0] = f.x; v[i*4+1] = f.y; v[i*4+2] = f.z; v[i*4+3] = f.w;
        s  += f.x + f.y + f.z + f.w;
        s2 += f.x*f.x + f.y*f.y + f.z*f.z + f.w*f.w;
    }
    for (int o = 32; o; o >>= 1) { s += __shfl_xor(s, o); s2 += __shfl_xor(s2, o); }
    const float m  = s * (1.f / DIM);
    const float var = s2 * (1.f / DIM) - m * m;
    const float rs = rsqrtf(var + 1e-5f);
    u16* orow = out + (long)row * DIM;
    #pragma unroll
    for (int i = 0; i < 3; i++) {
        const int c = i * 256 + lane * 4;
        ushort4 o4 = make_ushort4(
            f2bf((v[i*4+0] - m) * rs * g[c+0] + b[c+0]),
            f2bf((v[i*4+1] - m) * rs * g[c+1] + b[c+1]),
            f2bf((v[i*4+2] - m) * rs * g[c+2] + b[c+2]),
            f2bf((v[i*4+3] - m) * rs * g[c+3] + b[c+3]));
        *(ushort4*)&orow[c] = o4;
    }
}

// fp32 -> bf16 bulk convert (grid covers total/4 exactly)
__global__ __launch_bounds__(256)
void tobf16_kernel(const float* __restrict__ in, u16* __restrict__ out)
{
    const long i = ((long)blockIdx.x * 256 + threadIdx.x) * 4;
    const float4 f = *(const float4*)&in[i];
    *(ushort4*)&out[i] = make_ushort4(f2bf(f.x), f2bf(f.y), f2bf(f.z), f2bf(f.w));
}

// ghost dequant: w[o,k] = bf16(lut[idx[o,k]] * scale[o])
__global__ __launch_bounds__(256)
void dequant_kernel(const int* __restrict__ gidx, const float* __restrict__ scale,
                    const float* __restrict__ lut, u16* __restrict__ w,
                    long total, int Kd)
{
    __shared__ float slut[256];
    slut[threadIdx.x] = lut[threadIdx.x];
    __syncthreads();
    const long i4 = ((long)blockIdx.x * 256 + threadIdx.x) * 4;
    if (i4 >= total) return;
    const int4 g = *(const int4*)&gidx[i4];
    const float sc = scale[(int)(i4 / Kd)];
    *(ushort4*)&w[i4] = make_ushort4(f2bf(slut[g.x] * sc), f2bf(slut[g.y] * sc),
                                     f2bf(slut[g.z] * sc), f2bf(slut[g.w] * sc));
}

extern "C" void kernel_launch(void* const* d_in, const int* in_sizes, int n_in,
                              void* d_out, int out_size, void* d_ws, size_t ws_size,
                              hipStream_t stream)
{
    const float* lut        = (const float*)d_in[0];
    const float* tok_emb    = (const float*)d_in[1];
    const float* pos_emb    = (const float*)d_in[2];
    const float* ln1_g      = (const float*)d_in[3];
    const float* ln1_b      = (const float*)d_in[4];
    const float* in_w       = (const float*)d_in[5];
    const float* in_b       = (const float*)d_in[6];
    const float* out_w      = (const float*)d_in[7];
    const float* out_b      = (const float*)d_in[8];
    const float* ln2_g      = (const float*)d_in[9];
    const float* ln2_b      = (const float*)d_in[10];
    const float* mlp1_scale = (const float*)d_in[11];
    const float* mlp2_scale = (const float*)d_in[12];
    const float* lnf_g      = (const float*)d_in[13];
    const float* lnf_b      = (const float*)d_in[14];
    const float* head_scale = (const float*)d_in[15];
    const int*   mlp1_idx   = (const int*)d_in[16];
    const int*   mlp2_idx   = (const int*)d_in[17];
    const int*   head_idx   = (const int*)d_in[18];
    const int*   tokids     = (const int*)d_in[19];

    char* p = (char*)d_ws;
    auto alloc = [&](size_t bytes) { char* r = p; p += (bytes + 255) & ~(size_t)255; return r; };
    float* x    = (float*)alloc((size_t)NTOK * DIM * 4);
    u16*  h     = (u16*) alloc((size_t)NTOK * DIM * 2);
    u16*  h2    = (u16*) alloc((size_t)NTOK * HID * 2);
    u16*  qb    = (u16*) alloc((size_t)BHB * SEQ * HD * 2);
    u16*  kb    = (u16*) alloc((size_t)BHB * SEQ * HD * 2);
    u16*  vtb   = (u16*) alloc((size_t)BHB * SEQ * HD * 2);
    u16*  ob    = (u16*) alloc((size_t)NTOK * DIM * 2);
    u16*  inw16 = (u16*) alloc((size_t)NL * 3 * DIM * DIM * 2);
    u16*  outw16= (u16*) alloc((size_t)NL * DIM * DIM * 2);
    u16*  w1    = (u16*) alloc((size_t)HID * DIM * 2);
    u16*  w2    = (u16*) alloc((size_t)DIM * HID * 2);
    u16*  hw    = (u16*) alloc((size_t)VOCAB * DIM * 2);

    embed_kernel<<<NTOK * 192 / 256, 256, 0, stream>>>(tokids, tok_emb, pos_emb, x);
    tobf16_kernel<<<NL * 3 * DIM * DIM / 1024, 256, 0, stream>>>(in_w, inw16);
    tobf16_kernel<<<NL * DIM * DIM / 1024, 256, 0, stream>>>(out_w, outw16);
    {
        const long total = (long)VOCAB * DIM;
        const int blocks = (int)((total / 4 + 255) / 256);
        dequant_kernel<<<blocks, 256, 0, stream>>>(head_idx, head_scale, lut, hw, total, DIM);
    }

    for (int l = 0; l < NL; l++) {
        ln_kernel<<<NTOK / 4, 256, 0, stream>>>(x, ln1_g + l * DIM, ln1_b + l * DIM, h);
        gemm_bt<4, 1><<<dim3(NTOK / 128, 3 * DIM / 128, 1), 256, 0, stream>>>(
            h, inw16 + (long)l * 3 * DIM * DIM, in_b + l * 3 * DIM, nullptr,
            qb, kb, vtb, NTOK, 3 * DIM, DIM, 0, 0, 0);
        attn_kernel<<<dim3(BHB, 4), 256, 0, stream>>>(qb, kb, vtb, ob);
        gemm_bt<2, 3><<<dim3(NTOK / 128, DIM / 64, 1), 256, 0, stream>>>(
            ob, outw16 + (long)l * DIM * DIM, out_b + l * DIM, x,
            x, nullptr, nullptr, NTOK, DIM, DIM, 0, 0, 0);
        ln_kernel<<<NTOK / 4, 256, 0, stream>>>(x, ln2_g + l * DIM, ln2_b + l * DIM, h);
        dequant_kernel<<<HID * DIM / 1024, 256, 0, stream>>>(
            mlp1_idx + (long)l * HID * DIM, mlp1_scale + l * HID, lut, w1, (long)HID * DIM, DIM);
        gemm_bt<4, 4><<<dim3(NTOK / 128, HID / 128, 1), 256, 0, stream>>>(
            h, w1, nullptr, nullptr, h2, nullptr, nullptr, NTOK, HID, DIM, 0, 0, 0);
        dequant_kernel<<<DIM * HID / 1024, 256, 0, stream>>>(
            mlp2_idx + (long)l * DIM * HID, mlp2_scale + l * DIM, lut, w2, (long)DIM * HID, HID);
        gemm_bt<2, 3><<<dim3(NTOK / 128, DIM / 64, 1), 256, 0, stream>>>(
            h2, w2, nullptr, x, x, nullptr, nullptr, NTOK, DIM, HID, 0, 0, 0);
    }

    ln_kernel<<<NTOK / 4, 256, 0, stream>>>(x, lnf_g, lnf_b, h);
    gemm_bt<4, 0><<<dim3(NTOK / 128, (VOCAB + 127) / 128, 1), 256, 0, stream>>>(
        h, hw, nullptr, nullptr, d_out, nullptr, nullptr, NTOK, VOCAB, DIM, 0, 0, 0);
}

// Round 3
// 2935.121 us; speedup vs baseline: 1.4176x; 1.1324x over previous
//
#include <hip/hip_runtime.h>
#include <stdint.h>

#define DIM 768
#define NL 13
#define NH 12
#define VOCAB 50257
#define SEQ 512
#define BATCH 4
#define HID 3072
#define HD 64
#define NTOK (BATCH*SEQ)   // 2048
#define BHB (BATCH*NH)     // 48 batched heads

typedef unsigned short u16;
typedef __attribute__((ext_vector_type(8))) __bf16 bf16x8;
typedef __attribute__((ext_vector_type(4))) float f32x4;

__device__ __forceinline__ u16 f2bf(float f) {
    union { float f; uint32_t u; } v; v.f = f;
    uint32_t u = v.u;
    return (u16)((u + 0x7FFFu + ((u >> 16) & 1u)) >> 16);   // RNE
}

__device__ __forceinline__ void gl2lds16(const void* g, void* l) {
    // async global->LDS, 16B/lane; LDS dest = wave-uniform base + lane*16
    __builtin_amdgcn_global_load_lds((const __attribute__((address_space(1))) void*)g,
                                     (__attribute__((address_space(3))) void*)l,
                                     16, 0, 0);
}

__device__ __forceinline__ float gelu_tanh(float x) {
    float x3 = x * x * x;
    float t = tanhf(0.7978845608028654f * (x + 0.044715f * x3));
    return 0.5f * x * (1.0f + t);
}

// ---------------------------------------------------------------------------
// Shared epilogue for both GEMM variants.
// EPI: 0 plain f32 (col-bound checked), 1 qkv scatter, 3 f32 + bias + residual,
//      4 gelu -> bf16
// ---------------------------------------------------------------------------
template<int EPI>
__device__ __forceinline__ void epi_store(float v, int r, int c, int N, int z, long sC,
                                          const float* bias, const float* resid,
                                          void* out0, void* out1, void* out2)
{
    if constexpr (EPI == 0) {
        if (c < N) ((float*)out0)[(long)z * sC + (long)r * N + c] = v;
    } else if constexpr (EPI == 1) {
        v += bias[c];
        const int part = c / DIM;
        const int cc = c - part * DIM;
        const int hh = cc >> 6, d = cc & 63;
        const int b = r >> 9, t = r & 511;
        const int bh = b * NH + hh;
        if (part == 0)      ((u16*)out0)[((long)bh * SEQ + t) * HD + d] = f2bf(v);
        else if (part == 1) ((u16*)out1)[((long)bh * SEQ + t) * HD + d] = f2bf(v);
        else                ((u16*)out2)[((long)bh * HD + d) * SEQ + t] = f2bf(v);
    } else if constexpr (EPI == 3) {
        if (bias) v += bias[c];
        v += resid[(long)r * N + c];
        ((float*)out0)[(long)r * N + c] = v;
    } else {
        ((u16*)out0)[(long)r * N + c] = f2bf(gelu_tanh(v));
    }
}

// ---------------------------------------------------------------------------
// GEMM: C = A @ B^T.  A:[M,K] bf16 row-major, B:[N,K] bf16 row-major.
// 128 x (WN*32) tile, BK=32, 256 threads = 4 waves in 2x2, wave does 64 x (WN*16).
// double-buffered LDS, XOR k-chunk swizzle (source-side pre-swizzle for
// global_load_lds), bijective XCD-aware block remap.  Used for the big head GEMM.
// ---------------------------------------------------------------------------
template<int WN, int EPI>
__global__ __launch_bounds__(256)
void gemm_bt(const u16* __restrict__ A, const u16* __restrict__ B,
             const float* __restrict__ bias, const float* __restrict__ resid,
             void* __restrict__ out0, void* __restrict__ out1, void* __restrict__ out2,
             int M, int N, int K, long sA, long sB, long sC)
{
    constexpr int TN = WN * 32;
    __shared__ __align__(16) u16 As[2 * 128 * 32];
    __shared__ __align__(16) u16 Bs[2 * TN * 32];

    const int tid  = threadIdx.x;
    const int wave = tid >> 6;
    const int lane = tid & 63;
    const int quad = lane >> 4;
    const int l16  = lane & 15;
    const int wm   = wave >> 1;
    const int wn   = wave & 1;

    int bx = blockIdx.x, by = blockIdx.y;
    {
        const int gx = gridDim.x;
        const int nwg = gx * gridDim.y;
        const int orig = by * gx + bx;
        const int xcd = orig & 7;
        const int q = nwg >> 3, r = nwg & 7;
        const int wg = (xcd < r ? xcd * (q + 1) : r * (q + 1) + (xcd - r) * q) + (orig >> 3);
        bx = wg % gx; by = wg / gx;
    }

    const int m0 = bx * 128;
    const int n0 = by * TN;
    const int z  = blockIdx.z;

    const u16* Ab = A + (long)z * sA;
    const u16* Bb = B + (long)z * sB;

    const int srow = tid >> 2;          // 0..63
    const int scol = ((tid & 3) ^ ((srow >> 1) & 3)) * 8;   // pre-swizzled k-chunk

    u16* const asw0 = As + wave * 512;
    u16* const asw1 = As + 2048 + wave * 512;
    u16* const bsw0 = Bs + wave * 512;
    u16* const bsw1 = Bs + 2048 + wave * 512;   // WN==4 only

    const long aoff0 = (long)(m0 + srow) * K + scol;
    const long aoff1 = (long)(m0 + 64 + srow) * K + scol;
    int br0 = n0 + srow;      if (br0 > N - 1) br0 = N - 1;
    int br1 = n0 + 64 + srow; if (br1 > N - 1) br1 = N - 1;
    const long boff0 = (long)br0 * K + scol;
    const long boff1 = (long)br1 * K + scol;

    auto stage = [&](int b, int k0) {
        const int ao = b * 4096;
        const int bo = b * (TN * 32);
        gl2lds16(Ab + aoff0 + k0, asw0 + ao);
        gl2lds16(Ab + aoff1 + k0, asw1 + ao);
        gl2lds16(Bb + boff0 + k0, bsw0 + bo);
        if constexpr (WN == 4) gl2lds16(Bb + boff1 + k0, bsw1 + bo);
    };

    f32x4 acc[4][WN];
    #pragma unroll
    for (int i = 0; i < 4; i++)
        #pragma unroll
        for (int j = 0; j < WN; j++)
            acc[i][j] = (f32x4){0.f, 0.f, 0.f, 0.f};

    const int sq8 = (quad ^ ((l16 >> 1) & 3)) * 8;
    const int arow = (wm * 64 + l16) * 32 + sq8;
    const int brow = (wn * (WN * 16) + l16) * 32 + sq8;

    stage(0, 0);
    __syncthreads();

    int cur = 0;
    for (int k0 = 0; k0 < K; k0 += 32) {
        if (k0 + 32 < K) stage(cur ^ 1, k0 + 32);

        const u16* Ar = As + cur * 4096;
        const u16* Br = Bs + cur * (TN * 32);
        bf16x8 af[4], bfr[WN];
        #pragma unroll
        for (int i = 0; i < 4; i++)
            af[i] = *(const bf16x8*)&Ar[arow + i * 512];
        #pragma unroll
        for (int j = 0; j < WN; j++)
            bfr[j] = *(const bf16x8*)&Br[brow + j * 512];
        #pragma unroll
        for (int i = 0; i < 4; i++)
            #pragma unroll
            for (int j = 0; j < WN; j++)
                acc[i][j] = __builtin_amdgcn_mfma_f32_16x16x32_bf16(af[i], bfr[j], acc[i][j], 0, 0, 0);

        __syncthreads();
        cur ^= 1;
    }

    const int rbase = m0 + wm * 64;
    const int cbase = n0 + wn * (WN * 16);
    #pragma unroll
    for (int i = 0; i < 4; i++)
        #pragma unroll
        for (int j = 0; j < WN; j++)
            #pragma unroll
            for (int rg = 0; rg < 4; rg++)
                epi_store<EPI>(acc[i][j][rg], rbase + i * 16 + quad * 4 + rg,
                               cbase + j * 16 + l16, N, z, sC, bias, resid, out0, out1, out2);
}

// ---------------------------------------------------------------------------
// Small-M GEMM variant: 64 x (WN*32) tile, 4 waves in 2x2, wave does 32 x (WN*16).
// Same 2-phase dbuf + swizzle structure; 16-24KB LDS -> multiple blocks/CU so
// co-resident blocks hide each other's staging drain (grids 384-768 blocks).
// Used for the per-layer GEMMs whose grids starve at 128-row tiles.
// ---------------------------------------------------------------------------
template<int WN, int EPI>
__global__ __launch_bounds__(256)
void gemm_bt_s(const u16* __restrict__ A, const u16* __restrict__ B,
               const float* __restrict__ bias, const float* __restrict__ resid,
               void* __restrict__ out0, void* __restrict__ out1, void* __restrict__ out2,
               int M, int N, int K)
{
    constexpr int TN = WN * 32;
    __shared__ __align__(16) u16 As[2 * 64 * 32];
    __shared__ __align__(16) u16 Bs[2 * TN * 32];

    const int tid  = threadIdx.x;
    const int wave = tid >> 6;
    const int lane = tid & 63;
    const int quad = lane >> 4;
    const int l16  = lane & 15;
    const int wm   = wave >> 1;
    const int wn   = wave & 1;

    int bx = blockIdx.x, by = blockIdx.y;
    {
        const int gx = gridDim.x;
        const int nwg = gx * gridDim.y;
        const int orig = by * gx + bx;
        const int xcd = orig & 7;
        const int q = nwg >> 3, r = nwg & 7;
        const int wg = (xcd < r ? xcd * (q + 1) : r * (q + 1) + (xcd - r) * q) + (orig >> 3);
        bx = wg % gx; by = wg / gx;
    }

    const int m0 = bx * 64;
    const int n0 = by * TN;

    const int srow = tid >> 2;          // 0..63
    const int scol = ((tid & 3) ^ ((srow >> 1) & 3)) * 8;   // pre-swizzled k-chunk

    u16* const asw  = As + wave * 512;
    u16* const bsw0 = Bs + wave * 512;
    u16* const bsw1 = Bs + 2048 + wave * 512;   // WN==4 only

    const long aoff = (long)(m0 + srow) * K + scol;
    int br0 = n0 + srow;      if (br0 > N - 1) br0 = N - 1;
    int br1 = n0 + 64 + srow; if (br1 > N - 1) br1 = N - 1;
    const long boff0 = (long)br0 * K + scol;
    const long boff1 = (long)br1 * K + scol;

    auto stage = [&](int b, int k0) {
        gl2lds16(A + aoff + k0, asw + b * 2048);
        gl2lds16(B + boff0 + k0, bsw0 + b * (TN * 32));
        if constexpr (WN == 4) gl2lds16(B + boff1 + k0, bsw1 + b * (TN * 32));
    };

    f32x4 acc[2][WN];
    #pragma unroll
    for (int i = 0; i < 2; i++)
        #pragma unroll
        for (int j = 0; j < WN; j++)
            acc[i][j] = (f32x4){0.f, 0.f, 0.f, 0.f};

    const int sq8 = (quad ^ ((l16 >> 1) & 3)) * 8;
    const int arow = (wm * 32 + l16) * 32 + sq8;
    const int brow = (wn * (WN * 16) + l16) * 32 + sq8;

    stage(0, 0);
    __syncthreads();

    int cur = 0;
    for (int k0 = 0; k0 < K; k0 += 32) {
        if (k0 + 32 < K) stage(cur ^ 1, k0 + 32);

        const u16* Ar = As + cur * 2048;
        const u16* Br = Bs + cur * (TN * 32);
        bf16x8 af[2], bfr[WN];
        #pragma unroll
        for (int i = 0; i < 2; i++)
            af[i] = *(const bf16x8*)&Ar[arow + i * 512];
        #pragma unroll
        for (int j = 0; j < WN; j++)
            bfr[j] = *(const bf16x8*)&Br[brow + j * 512];
        #pragma unroll
        for (int i = 0; i < 2; i++)
            #pragma unroll
            for (int j = 0; j < WN; j++)
                acc[i][j] = __builtin_amdgcn_mfma_f32_16x16x32_bf16(af[i], bfr[j], acc[i][j], 0, 0, 0);

        __syncthreads();
        cur ^= 1;
    }

    const int rbase = m0 + wm * 32;
    const int cbase = n0 + wn * (WN * 16);
    #pragma unroll
    for (int i = 0; i < 2; i++)
        #pragma unroll
        for (int j = 0; j < WN; j++)
            #pragma unroll
            for (int rg = 0; rg < 4; rg++)
                epi_store<EPI>(acc[i][j][rg], rbase + i * 16 + quad * 4 + rg,
                               cbase + j * 16 + l16, N, 0, 0, bias, resid, out0, out1, out2);
}

// ---------------------------------------------------------------------------
// Fused flash attention (unchanged from round 2).
// ---------------------------------------------------------------------------
__global__ __launch_bounds__(256)
void attn_kernel(const u16* __restrict__ qb, const u16* __restrict__ kb,
                 const u16* __restrict__ vtb, u16* __restrict__ ob)
{
    __shared__ __align__(16) u16 Ks[512 * 64];     // 64KB  [kv][d]
    __shared__ __align__(16) u16 Vs[64 * 512];     // 64KB  [d][kv] (V^T)
    __shared__ __align__(16) u16 Ps[4][32 * 64];   // 16KB  per-wave P tile

    const int tid  = threadIdx.x;
    const int wave = tid >> 6;
    const int lane = tid & 63;
    const int quad = lane >> 4;
    const int l16  = lane & 15;

    const int bh   = blockIdx.x;
    const int qblk = blockIdx.y;
    const int qr0  = qblk * 128 + wave * 32;

    #pragma unroll 4
    for (int cI = 0; cI < 16; ++cI) {
        const int rbase = cI * 32 + wave * 8;
        const int r  = rbase + (lane >> 3);
        const int ch = lane & 7;
        gl2lds16(kb + ((long)bh * SEQ + r) * HD + ((ch ^ (r & 7)) * 8), Ks + rbase * 64);
    }
    #pragma unroll 4
    for (int cI = 0; cI < 16; ++cI) {
        const int d = cI * 4 + wave;
        gl2lds16(vtb + ((long)bh * HD + d) * SEQ + ((lane ^ (d & 7)) * 8), Vs + d * 512);
    }

    bf16x8 af[2][2];
    const long qoff = ((long)bh * SEQ + qr0) * HD;
    #pragma unroll
    for (int i = 0; i < 2; i++)
        #pragma unroll
        for (int kc = 0; kc < 2; kc++)
            af[i][kc] = *(const bf16x8*)&qb[qoff + (long)(i * 16 + l16) * HD + kc * 32 + quad * 8];

    __syncthreads();   // drains vmcnt for the LDS staging

    f32x4 o[2][4];
    float mrun[2][4], lrun[2][4];
    #pragma unroll
    for (int i = 0; i < 2; i++)
        #pragma unroll
        for (int rg = 0; rg < 4; rg++) { mrun[i][rg] = -1e30f; lrun[i][rg] = 0.f; }
    #pragma unroll
    for (int i = 0; i < 2; i++)
        #pragma unroll
        for (int nd = 0; nd < 4; nd++)
            o[i][nd] = (f32x4){0.f, 0.f, 0.f, 0.f};

    u16* const Pw = &Ps[wave][0];
    const int rsw = l16 & 7;
    const int kvend = qr0 + 32;

    for (int kv0 = 0; kv0 < kvend; kv0 += 64) {
        f32x4 s[2][4];
        #pragma unroll
        for (int i = 0; i < 2; i++)
            #pragma unroll
            for (int n = 0; n < 4; n++)
                s[i][n] = (f32x4){0.f, 0.f, 0.f, 0.f};
        bf16x8 bf[4][2];
        #pragma unroll
        for (int n = 0; n < 4; n++)
            #pragma unroll
            for (int kc = 0; kc < 2; kc++)
                bf[n][kc] = *(const bf16x8*)&Ks[(kv0 + n * 16 + l16) * 64 + (((kc * 4 + quad) ^ rsw) * 8)];
        #pragma unroll
        for (int i = 0; i < 2; i++)
            #pragma unroll
            for (int n = 0; n < 4; n++)
                #pragma unroll
                for (int kc = 0; kc < 2; kc++)
                    s[i][n] = __builtin_amdgcn_mfma_f32_16x16x32_bf16(af[i][kc], bf[n][kc], s[i][n], 0, 0, 0);

        #pragma unroll
        for (int i = 0; i < 2; i++) {
            #pragma unroll
            for (int rg = 0; rg < 4; rg++) {
                const int q = qr0 + i * 16 + quad * 4 + rg;
                float v[4];
                #pragma unroll
                for (int n = 0; n < 4; n++) {
                    const int c = kv0 + n * 16 + l16;
                    v[n] = (c <= q) ? s[i][n][rg] * 0.125f : -1e30f;
                }
                float pm = fmaxf(fmaxf(v[0], v[1]), fmaxf(v[2], v[3]));
                #pragma unroll
                for (int off = 1; off < 16; off <<= 1) pm = fmaxf(pm, __shfl_xor(pm, off));
                const float mo = mrun[i][rg];
                const float mn = fmaxf(mo, pm);
                const float corr = __expf(mo - mn);
                float ps = 0.f;
                #pragma unroll
                for (int n = 0; n < 4; n++) { const float e = __expf(v[n] - mn); v[n] = e; ps += e; }
                #pragma unroll
                for (int off = 1; off < 16; off <<= 1) ps += __shfl_xor(ps, off);
                lrun[i][rg] = lrun[i][rg] * corr + ps;
                mrun[i][rg] = mn;
                #pragma unroll
                for (int nd = 0; nd < 4; nd++) o[i][nd][rg] *= corr;
                const int qlz = i * 16 + quad * 4 + rg;
                const int sw = qlz & 7;
                #pragma unroll
                for (int n = 0; n < 4; n++)
                    Pw[qlz * 64 + (((n * 2 + (l16 >> 3)) ^ sw) * 8) + (l16 & 7)] = f2bf(v[n]);
            }
        }
        asm volatile("s_waitcnt lgkmcnt(0)" ::: "memory");   // P writes visible wave-wide

        bf16x8 pa[2][2], vb[4][2];
        #pragma unroll
        for (int i = 0; i < 2; i++)
            #pragma unroll
            for (int kc = 0; kc < 2; kc++)
                pa[i][kc] = *(const bf16x8*)&Pw[(i * 16 + l16) * 64 + (((kc * 4 + quad) ^ rsw) * 8)];
        #pragma unroll
        for (int nd = 0; nd < 4; nd++)
            #pragma unroll
            for (int kc = 0; kc < 2; kc++)
                vb[nd][kc] = *(const bf16x8*)&Vs[(nd * 16 + l16) * 512 + ((((kv0 >> 3) + kc * 4 + quad) ^ rsw) * 8)];
        #pragma unroll
        for (int i = 0; i < 2; i++)
            #pragma unroll
            for (int nd = 0; nd < 4; nd++)
                #pragma unroll
                for (int kc = 0; kc < 2; kc++)
                    o[i][nd] = __builtin_amdgcn_mfma_f32_16x16x32_bf16(pa[i][kc], vb[nd][kc], o[i][nd], 0, 0, 0);
    }

    const int b  = bh / NH, hh = bh - b * NH;
    #pragma unroll
    for (int i = 0; i < 2; i++) {
        #pragma unroll
        for (int rg = 0; rg < 4; rg++) {
            const float inv = 1.f / lrun[i][rg];
            const int t = qr0 + i * 16 + quad * 4 + rg;
            u16* orow = ob + ((long)(b * SEQ + t)) * DIM + hh * HD;
            #pragma unroll
            for (int nd = 0; nd < 4; nd++)
                orow[nd * 16 + l16] = f2bf(o[i][nd][rg] * inv);
        }
    }
}

// x = tok_emb[idx] + pos_emb ; fp32 out
__global__ __launch_bounds__(256)
void embed_kernel(const int* __restrict__ tokidx, const float* __restrict__ tok,
                  const float* __restrict__ pos, float* __restrict__ x)
{
    const int i = blockIdx.x * 256 + threadIdx.x;   // float4 index over NTOK*192
    const int row = i / 192;
    const int c4 = i - row * 192;
    const int t = row & (SEQ - 1);
    const int tk = tokidx[row];
    const float4 a = *(const float4*)&tok[(long)tk * DIM + c4 * 4];
    const float4 p = *(const float4*)&pos[(long)t * DIM + c4 * 4];
    *(float4*)&x[(long)row * DIM + c4 * 4] = make_float4(a.x + p.x, a.y + p.y, a.z + p.z, a.w + p.w);
}

// LayerNorm over DIM=768, one wave per row, bf16 out
__global__ __launch_bounds__(256)
void ln_kernel(const float* __restrict__ x, const float* __restrict__ g,
               const float* __restrict__ b, u16* __restrict__ out)
{
    const int row = blockIdx.x * 4 + (threadIdx.x >> 6);
    const int lane = threadIdx.x & 63;
    const float* xr = x + (long)row * DIM;
    float v[12];
    float s = 0.f, s2 = 0.f;
    #pragma unroll
    for (int i = 0; i < 3; i++) {
        const float4 f = *(const float4*)&xr[i * 256 + lane * 4];
        v[i*4+0] = f.x; v[i*4+1] = f.y; v[i*4+2] = f.z; v[i*4+3] = f.w;
        s  += f.x + f.y + f.z + f.w;
        s2 += f.x*f.x + f.y*f.y + f.z*f.z + f.w*f.w;
    }
    for (int o = 32; o; o >>= 1) { s += __shfl_xor(s, o); s2 += __shfl_xor(s2, o); }
    const float m  = s * (1.f / DIM);
    const float var = s2 * (1.f / DIM) - m * m;
    const float rs = rsqrtf(var + 1e-5f);
    u16* orow = out + (long)row * DIM;
    #pragma unroll
    for (int i = 0; i < 3; i++) {
        const int c = i * 256 + lane * 4;
        ushort4 o4 = make_ushort4(
            f2bf((v[i*4+0] - m) * rs * g[c+0] + b[c+0]),
            f2bf((v[i*4+1] - m) * rs * g[c+1] + b[c+1]),
            f2bf((v[i*4+2] - m) * rs * g[c+2] + b[c+2]),
            f2bf((v[i*4+3] - m) * rs * g[c+3] + b[c+3]));
        *(ushort4*)&orow[c] = o4;
    }
}

// fp32 -> bf16 bulk convert (grid covers total/4 exactly)
__global__ __launch_bounds__(256)
void tobf16_kernel(const float* __restrict__ in, u16* __restrict__ out)
{
    const long i = ((long)blockIdx.x * 256 + threadIdx.x) * 4;
    const float4 f = *(const float4*)&in[i];
    *(ushort4*)&out[i] = make_ushort4(f2bf(f.x), f2bf(f.y), f2bf(f.z), f2bf(f.w));
}

// ghost dequant: w[o,k] = bf16(lut[idx[o,k]] * scale[o])
__global__ __launch_bounds__(256)
void dequant_kernel(const int* __restrict__ gidx, const float* __restrict__ scale,
                    const float* __restrict__ lut, u16* __restrict__ w,
                    long total, int Kd)
{
    __shared__ float slut[256];
    slut[threadIdx.x] = lut[threadIdx.x];
    __syncthreads();
    const long i4 = ((long)blockIdx.x * 256 + threadIdx.x) * 4;
    if (i4 >= total) return;
    const int4 g = *(const int4*)&gidx[i4];
    const float sc = scale[(int)(i4 / Kd)];
    *(ushort4*)&w[i4] = make_ushort4(f2bf(slut[g.x] * sc), f2bf(slut[g.y] * sc),
                                     f2bf(slut[g.z] * sc), f2bf(slut[g.w] * sc));
}

extern "C" void kernel_launch(void* const* d_in, const int* in_sizes, int n_in,
                              void* d_out, int out_size, void* d_ws, size_t ws_size,
                              hipStream_t stream)
{
    const float* lut        = (const float*)d_in[0];
    const float* tok_emb    = (const float*)d_in[1];
    const float* pos_emb    = (const float*)d_in[2];
    const float* ln1_g      = (const float*)d_in[3];
    const float* ln1_b      = (const float*)d_in[4];
    const float* in_w       = (const float*)d_in[5];
    const float* in_b       = (const float*)d_in[6];
    const float* out_w      = (const float*)d_in[7];
    const float* out_b      = (const float*)d_in[8];
    const float* ln2_g      = (const float*)d_in[9];
    const float* ln2_b      = (const float*)d_in[10];
    const float* mlp1_scale = (const float*)d_in[11];
    const float* mlp2_scale = (const float*)d_in[12];
    const float* lnf_g      = (const float*)d_in[13];
    const float* lnf_b      = (const float*)d_in[14];
    const float* head_scale = (const float*)d_in[15];
    const int*   mlp1_idx   = (const int*)d_in[16];
    const int*   mlp2_idx   = (const int*)d_in[17];
    const int*   head_idx   = (const int*)d_in[18];
    const int*   tokids     = (const int*)d_in[19];

    char* p = (char*)d_ws;
    auto alloc = [&](size_t bytes) { char* r = p; p += (bytes + 255) & ~(size_t)255; return r; };
    float* x    = (float*)alloc((size_t)NTOK * DIM * 4);
    u16*  h     = (u16*) alloc((size_t)NTOK * DIM * 2);
    u16*  h2    = (u16*) alloc((size_t)NTOK * HID * 2);
    u16*  qb    = (u16*) alloc((size_t)BHB * SEQ * HD * 2);
    u16*  kb    = (u16*) alloc((size_t)BHB * SEQ * HD * 2);
    u16*  vtb   = (u16*) alloc((size_t)BHB * SEQ * HD * 2);
    u16*  ob    = (u16*) alloc((size_t)NTOK * DIM * 2);
    u16*  inw16 = (u16*) alloc((size_t)NL * 3 * DIM * DIM * 2);
    u16*  outw16= (u16*) alloc((size_t)NL * DIM * DIM * 2);
    u16*  w1    = (u16*) alloc((size_t)HID * DIM * 2);
    u16*  w2    = (u16*) alloc((size_t)DIM * HID * 2);
    u16*  hw    = (u16*) alloc((size_t)VOCAB * DIM * 2);

    embed_kernel<<<NTOK * 192 / 256, 256, 0, stream>>>(tokids, tok_emb, pos_emb, x);
    tobf16_kernel<<<NL * 3 * DIM * DIM / 1024, 256, 0, stream>>>(in_w, inw16);
    tobf16_kernel<<<NL * DIM * DIM / 1024, 256, 0, stream>>>(out_w, outw16);
    {
        const long total = (long)VOCAB * DIM;
        const int blocks = (int)((total / 4 + 255) / 256);
        dequant_kernel<<<blocks, 256, 0, stream>>>(head_idx, head_scale, lut, hw, total, DIM);
    }

    for (int l = 0; l < NL; l++) {
        ln_kernel<<<NTOK / 4, 256, 0, stream>>>(x, ln1_g + l * DIM, ln1_b + l * DIM, h);
        gemm_bt_s<4, 1><<<dim3(NTOK / 64, 3 * DIM / 128), 256, 0, stream>>>(
            h, inw16 + (long)l * 3 * DIM * DIM, in_b + l * 3 * DIM, nullptr,
            qb, kb, vtb, NTOK, 3 * DIM, DIM);
        attn_kernel<<<dim3(BHB, 4), 256, 0, stream>>>(qb, kb, vtb, ob);
        gemm_bt_s<2, 3><<<dim3(NTOK / 64, DIM / 64), 256, 0, stream>>>(
            ob, outw16 + (long)l * DIM * DIM, out_b + l * DIM, x,
            x, nullptr, nullptr, NTOK, DIM, DIM);
        ln_kernel<<<NTOK / 4, 256, 0, stream>>>(x, ln2_g + l * DIM, ln2_b + l * DIM, h);
        dequant_kernel<<<HID * DIM / 1024, 256, 0, stream>>>(
            mlp1_idx + (long)l * HID * DIM, mlp1_scale + l * HID, lut, w1, (long)HID * DIM, DIM);
        gemm_bt_s<4, 4><<<dim3(NTOK / 64, HID / 128), 256, 0, stream>>>(
            h, w1, nullptr, nullptr, h2, nullptr, nullptr, NTOK, HID, DIM);
        dequant_kernel<<<DIM * HID / 1024, 256, 0, stream>>>(
            mlp2_idx + (long)l * DIM * HID, mlp2_scale + l * DIM, lut, w2, (long)DIM * HID, HID);
        gemm_bt_s<2, 3><<<dim3(NTOK / 64, DIM / 64), 256, 0, stream>>>(
            h2, w2, nullptr, x, x, nullptr, nullptr, NTOK, DIM, HID);
    }

    ln_kernel<<<NTOK / 4, 256, 0, stream>>>(x, lnf_g, lnf_b, h);
    gemm_bt<4, 0><<<dim3(NTOK / 128, (VOCAB + 127) / 128, 1), 256, 0, stream>>>(
        h, hw, nullptr, nullptr, d_out, nullptr, nullptr, NTOK, VOCAB, DIM, 0, 0, 0);
}